// Round 13
// baseline (374.951 us; speedup 1.0000x reference)
//
#include <hip/hip_runtime.h>

#define N_NODES 20000
#define N_EDGES 640000
#define D 128
#define CAP 128           // ELL capacity per node
#define NBK 625           // buckets of 32 nodes (625*32 = 20000 exactly)
#define BCAP 1280         // bucket capacity (mean 1024, sigma 32, z=8)
#define NB_AGG 40000      // one 64-thread wave per (node, 64-feat slice): 20000 x 2
#define NB_CHAIN 129      // chain rider blocks: one row of [A;a](129x128)@B each
#define SPMV_BLOCKS 313   // ceil(20000/64)
#define NB_SCAT 625       // 640K/4 edges / 256
#define NB_H2BF 1250      // 20000*16 uint4 / 256
#define TM 32             // final-GEMM tile rows

typedef unsigned int uint;
typedef unsigned short ushort;

__device__ __forceinline__ float bflo(uint u) { return __uint_as_float(u << 16); }
__device__ __forceinline__ float bfhi(uint u) { return __uint_as_float(u & 0xffff0000u); }
__device__ __forceinline__ uint pack2bf(float lo, float hi) {
    uint a = __float_as_uint(lo), b = __float_as_uint(hi);
    a += 0x7fffu + ((a >> 16) & 1u);
    b += 0x7fffu + ((b >> 16) & 1u);
    return (a >> 16) | (b & 0xffff0000u);
}

// ---------------- bcnt = 0 (625 ints) ----------------

__global__ void zero_bcnt_kernel(int* __restrict__ bcnt) {
    int i = threadIdx.x;
    if (i < NBK) bcnt[i] = 0;
}

// ---------------- phase 1: edge->bucket FIFO (blocks 0..624) + h->bf16 (rest) ----------------
// Bucket writes are cursor-sequential -> L2 lines fill before writeback (no sector churn).

__global__ void phase1_kernel(const int4* __restrict__ src4, const int4* __restrict__ dst4,
                              int* __restrict__ bcnt, uint* __restrict__ bbuf,
                              const float4* __restrict__ hin, uint4* __restrict__ hbf) {
    int bid = blockIdx.x;
    int t = threadIdx.x;
    if (bid < NB_SCAT) {
        int e4 = bid * 256 + t;
        int4 s = src4[e4];
        int4 d = dst4[e4];
        int b;
        b = d.x >> 5; bbuf[b * BCAP + atomicAdd(&bcnt[b], 1)] = ((uint)(d.x & 31) << 16) | (uint)s.x;
        b = d.y >> 5; bbuf[b * BCAP + atomicAdd(&bcnt[b], 1)] = ((uint)(d.y & 31) << 16) | (uint)s.y;
        b = d.z >> 5; bbuf[b * BCAP + atomicAdd(&bcnt[b], 1)] = ((uint)(d.z & 31) << 16) | (uint)s.z;
        b = d.w >> 5; bbuf[b * BCAP + atomicAdd(&bcnt[b], 1)] = ((uint)(d.w & 31) << 16) | (uint)s.w;
    } else {
        int i = (bid - NB_SCAT) * 256 + t;   // uint4 index
        float4 f0 = hin[i * 2];
        float4 f1 = hin[i * 2 + 1];
        uint4 o;
        o.x = pack2bf(f0.x, f0.y); o.y = pack2bf(f0.z, f0.w);
        o.z = pack2bf(f1.x, f1.y); o.w = pack2bf(f1.z, f1.w);
        hbf[i] = o;
    }
}

// ---------------- phase 2: bucket -> ELL via LDS; coalesced row writes; cnt stored directly ----------------

__global__ __launch_bounds__(256) void phase2_kernel(const int* __restrict__ bcnt,
                                                     const uint* __restrict__ bbuf,
                                                     int* __restrict__ cnt,
                                                     ushort* __restrict__ slot) {
    __shared__ int lcnt[32];
    __shared__ ushort lslot[32 * CAP];   // 8 KB
    int b = blockIdx.x;
    int t = threadIdx.x;
    if (t < 32) lcnt[t] = 0;
    __syncthreads();
    int n = bcnt[b];
    for (int i = t; i < n; i += 256) {
        uint e = bbuf[b * BCAP + i];
        int dl = (int)(e >> 16);
        int p = atomicAdd(&lcnt[dl], 1);
        lslot[dl * CAP + p] = (ushort)(e & 0xffffu);
    }
    __syncthreads();
    // coalesced write-out: 32 nodes x 128 ushorts = 512 uint4
    const uint4* ls4 = (const uint4*)lslot;
    uint4* gs4 = (uint4*)slot + (size_t)b * 32 * CAP / 8;
    for (int i = t; i < 32 * CAP / 8; i += 256) gs4[i] = ls4[i];
    if (t < 32) cnt[b * 32 + t] = lcnt[t];
}

// ---------------- fused agg pass (bf16 payloads, f32 accumulate) ----------------
// blocks [0, NB_AGG): one wave per (node, slice of 64 feats). Each edge-slice is
//   ONE 128B line. slice = (bid&7)>>2 keeps each slice's 2.56MB line set in an
//   XCD-quad's L2s (perf heuristic only). 8 slots x 8 lanes x uint4(8 bf16).
// blocks [NB_AGG, +129) when cO != null: chain row cO[row] = ([cA;cbias] @ cB)[row].
// remaining blocks when uout != null: degree SpMV.
//   uin != null:  uout[i] = uin[i] + sum uin[nbr]
//   uin == null:  uout[i] = 1+2c+sum cnt[nbr]  (= S·(1+deg))

__global__ __launch_bounds__(64) void agg_fused_kernel(
        const uint4* __restrict__ hbf, const int* __restrict__ cnt,
        const ushort* __restrict__ slot, uint4* __restrict__ xbf,
        const float* __restrict__ cA, const float* __restrict__ cbias,
        const float* __restrict__ cB, float* __restrict__ cO,
        const float* __restrict__ uin, float* __restrict__ uout) {
    int bid = blockIdx.x;
    int t = threadIdx.x;

    if (bid >= NB_AGG) {
        int cb = bid - NB_AGG;
        if (cO && cb < NB_CHAIN) {
            // chain: row cb of [cA; cbias^T] @ cB; 64 threads x 2 cols
            const float* Ar = (cb < 128) ? &cA[cb * 128] : cbias;
            int c0 = t, c1 = t + 64;
            float s0 = 0.f, s1 = 0.f;
            for (int k = 0; k < 128; ++k) {
                float a = Ar[k];
                s0 += a * cB[k * 128 + c0];
                s1 += a * cB[k * 128 + c1];
            }
            cO[cb * 128 + c0] = s0;
            cO[cb * 128 + c1] = s1;
        } else if (uout) {
            int sb = cb - (cO ? NB_CHAIN : 0);
            int node = sb * 64 + t;
            if (node < N_NODES) {
                int c = cnt[node];
                const ushort* sl = &slot[node * CAP];
                float s;
                if (uin) {
                    s = uin[node];
                    for (int k = 0; k < c; ++k) s += uin[sl[k]];
                } else {
                    s = 1.0f + 2.0f * (float)c;
                    for (int k = 0; k < c; ++k) s += (float)cnt[sl[k]];
                }
                uout[node] = s;
            }
        }
        return;
    }

    // ---- aggregation ----
    int r = bid & 7;
    int q = bid >> 3;
    int slice = r >> 2;           // 0..1 (fixed per block -> XCD-quad affinity)
    int node  = q * 4 + (r & 3);  // 0..19999
    int lo = node * CAP;
    int hi = lo + cnt[node];
    int slot8 = t >> 3;           // 0..7
    int fl    = t & 7;            // uint4 within the 8-uint4 slice
    int soff  = slice * 8 + fl;   // uint4 index within 16-uint4 row

    uint4 sv = hbf[(size_t)node * 16 + soff];   // self row slice, issued early

    float a0 = 0.f, a1 = 0.f, a2 = 0.f, a3 = 0.f;
    float a4 = 0.f, a5 = 0.f, a6 = 0.f, a7 = 0.f;

#define ACC8(v) do { \
        a0 += bflo((v).x); a1 += bfhi((v).x); \
        a2 += bflo((v).y); a3 += bfhi((v).y); \
        a4 += bflo((v).z); a5 += bfhi((v).z); \
        a6 += bflo((v).w); a7 += bfhi((v).w); } while (0)

    int k = lo + slot8;
    for (; k + 24 < hi; k += 32) {    // 4 line-gathers in flight per slot
        int s0 = slot[k];
        int s1 = slot[k + 8];
        int s2 = slot[k + 16];
        int s3 = slot[k + 24];
        uint4 v0 = hbf[(size_t)s0 * 16 + soff];
        uint4 v1 = hbf[(size_t)s1 * 16 + soff];
        uint4 v2 = hbf[(size_t)s2 * 16 + soff];
        uint4 v3 = hbf[(size_t)s3 * 16 + soff];
        ACC8(v0); ACC8(v1); ACC8(v2); ACC8(v3);
    }
    for (; k < hi; k += 8) {
        int s0 = slot[k];
        uint4 v0 = hbf[(size_t)s0 * 16 + soff];
        ACC8(v0);
    }
#undef ACC8

    // reduce across the 8 slots (lane bits 3,4,5)
    a0 += __shfl_xor(a0, 8);  a1 += __shfl_xor(a1, 8);
    a2 += __shfl_xor(a2, 8);  a3 += __shfl_xor(a3, 8);
    a4 += __shfl_xor(a4, 8);  a5 += __shfl_xor(a5, 8);
    a6 += __shfl_xor(a6, 8);  a7 += __shfl_xor(a7, 8);
    a0 += __shfl_xor(a0, 16); a1 += __shfl_xor(a1, 16);
    a2 += __shfl_xor(a2, 16); a3 += __shfl_xor(a3, 16);
    a4 += __shfl_xor(a4, 16); a5 += __shfl_xor(a5, 16);
    a6 += __shfl_xor(a6, 16); a7 += __shfl_xor(a7, 16);
    a0 += __shfl_xor(a0, 32); a1 += __shfl_xor(a1, 32);
    a2 += __shfl_xor(a2, 32); a3 += __shfl_xor(a3, 32);
    a4 += __shfl_xor(a4, 32); a5 += __shfl_xor(a5, 32);
    a6 += __shfl_xor(a6, 32); a7 += __shfl_xor(a7, 32);

    if (t < 8) {   // slot 0, fl == t
        a0 += bflo(sv.x); a1 += bfhi(sv.x);
        a2 += bflo(sv.y); a3 += bfhi(sv.y);
        a4 += bflo(sv.z); a5 += bfhi(sv.z);
        a6 += bflo(sv.w); a7 += bfhi(sv.w);
        uint4 o;
        o.x = pack2bf(a0, a1); o.y = pack2bf(a2, a3);
        o.z = pack2bf(a4, a5); o.w = pack2bf(a6, a7);
        xbf[(size_t)node * 16 + soff] = o;
    }
}

// ---------------- final GEMM: out = g @ WP + uc⊗v4 + ub⊗v3 + (1+cnt)⊗v2 + 1⊗b3 ----------------

__global__ __launch_bounds__(256) void gemm_kernel(const uint4* __restrict__ xb,
                                                   const float* __restrict__ W,
                                                   float* __restrict__ out,
                                                   const int* __restrict__ cnt,
                                                   const float* __restrict__ ub,
                                                   const float* __restrict__ uc,
                                                   const float* __restrict__ v2p,
                                                   const float* __restrict__ v3p,
                                                   const float* __restrict__ v4p,
                                                   const float* __restrict__ v1p) {
    __shared__ float Xs[TM][D];
    int t = threadIdx.x;
    int row0 = blockIdx.x * TM;

    for (int i = t; i < TM * 16; i += 256) {
        int rr  = i >> 4;
        int c16 = i & 15;
        uint4 u = xb[(size_t)(row0 + rr) * 16 + c16];
        float4 f0 = make_float4(bflo(u.x), bfhi(u.x), bflo(u.y), bfhi(u.y));
        float4 f1 = make_float4(bflo(u.z), bfhi(u.z), bflo(u.w), bfhi(u.w));
        *((float4*)&Xs[rr][c16 * 8])     = f0;
        *((float4*)&Xs[rr][c16 * 8 + 4]) = f1;
    }
    __syncthreads();

    int cg = t & 31;
    int rg = t >> 5;
    int j0 = cg * 4;
    int r0 = rg * 4;

    float acc[4][4];
    #pragma unroll
    for (int i = 0; i < 4; ++i) {
        acc[i][0] = 0.f; acc[i][1] = 0.f; acc[i][2] = 0.f; acc[i][3] = 0.f;
    }

    for (int k4 = 0; k4 < D; k4 += 4) {
        float4 w0 = *((const float4*)&W[(k4 + 0) * D + j0]);
        float4 w1 = *((const float4*)&W[(k4 + 1) * D + j0]);
        float4 w2 = *((const float4*)&W[(k4 + 2) * D + j0]);
        float4 w3 = *((const float4*)&W[(k4 + 3) * D + j0]);
        #pragma unroll
        for (int i = 0; i < 4; ++i) {
            float4 xv = *((const float4*)&Xs[r0 + i][k4]);
            acc[i][0] += xv.x * w0.x; acc[i][0] += xv.y * w1.x;
            acc[i][0] += xv.z * w2.x; acc[i][0] += xv.w * w3.x;
            acc[i][1] += xv.x * w0.y; acc[i][1] += xv.y * w1.y;
            acc[i][1] += xv.z * w2.y; acc[i][1] += xv.w * w3.y;
            acc[i][2] += xv.x * w0.z; acc[i][2] += xv.y * w1.z;
            acc[i][2] += xv.z * w2.z; acc[i][2] += xv.w * w3.z;
            acc[i][3] += xv.x * w0.w; acc[i][3] += xv.y * w1.w;
            acc[i][3] += xv.z * w2.w; acc[i][3] += xv.w * w3.w;
        }
    }

    float4 v1 = *((const float4*)&v1p[j0]);
    float4 v2 = *((const float4*)&v2p[j0]);
    float4 v3 = *((const float4*)&v3p[j0]);
    float4 v4 = *((const float4*)&v4p[j0]);

    #pragma unroll
    for (int i = 0; i < 4; ++i) {
        int ra = row0 + r0 + i;
        float aa = 1.0f + (float)cnt[ra];
        float ab = ub[ra], ac = uc[ra];
        float o0 = acc[i][0] + ac * v4.x + ab * v3.x + aa * v2.x + v1.x;
        float o1 = acc[i][1] + ac * v4.y + ab * v3.y + aa * v2.y + v1.y;
        float o2 = acc[i][2] + ac * v4.z + ab * v3.z + aa * v2.z + v1.z;
        float o3 = acc[i][3] + ac * v4.w + ab * v3.w + aa * v2.w + v1.w;
        *((float4*)&out[(size_t)ra * D + j0]) = make_float4(o0, o1, o2, o3);
    }
}

// ---------------- launch ----------------

extern "C" void kernel_launch(void* const* d_in, const int* in_sizes, int n_in,
                              void* d_out, int out_size, void* d_ws, size_t ws_size,
                              hipStream_t stream) {
    const float* h   = (const float*)d_in[0];
    const int*   ei  = (const int*)d_in[1];
    const int*   src = ei;
    const int*   dst = ei + N_EDGES;
    const float* W0 = (const float*)d_in[2]; const float* b0 = (const float*)d_in[3];
    const float* W1 = (const float*)d_in[4]; const float* b1 = (const float*)d_in[5];
    const float* W2 = (const float*)d_in[6]; const float* b2 = (const float*)d_in[7];
    const float* W3 = (const float*)d_in[8]; const float* b3 = (const float*)d_in[9];
    float* out = (float*)d_out;

    char* ws = (char*)d_ws;
    auto alloc = [&](size_t bytes) {
        char* p = ws;
        ws += (bytes + 255) & ~(size_t)255;
        return p;
    };
    int*    cnt  = (int*)alloc(N_NODES * sizeof(int));
    int*    bcnt = (int*)alloc(NBK * sizeof(int));
    uint*   bbuf = (uint*)alloc((size_t)NBK * BCAP * sizeof(uint));
    ushort* slot = (ushort*)alloc((size_t)N_NODES * CAP * sizeof(ushort));
    uint4*  hbf  = (uint4*)alloc((size_t)N_NODES * 16 * sizeof(uint4));  // bf16 h
    uint4*  bufA = (uint4*)alloc((size_t)N_NODES * 16 * sizeof(uint4));
    uint4*  bufB = (uint4*)alloc((size_t)N_NODES * 16 * sizeof(uint4));
    float*  T2   = (float*)alloc(129 * D * sizeof(float));  // [W2W3 ; v2]
    float*  T3   = (float*)alloc(129 * D * sizeof(float));  // [W1W2W3 ; v3]
    float*  TW   = (float*)alloc(129 * D * sizeof(float));  // [W0W1W2W3 ; v4]
    float*  ub   = (float*)alloc(N_NODES * sizeof(float));  // S²·1
    float*  uc   = (float*)alloc(N_NODES * sizeof(float));  // S³·1

    // bcnt = 0
    zero_bcnt_kernel<<<1, 1024, 0, stream>>>(bcnt);

    // phase 1: edge->bucket FIFO + h->bf16 (fused riders)
    phase1_kernel<<<NB_SCAT + NB_H2BF, 256, 0, stream>>>(
        (const int4*)src, (const int4*)dst, bcnt, bbuf, (const float4*)h, hbf);

    // phase 2: bucket -> ELL (LDS), coalesced; cnt written directly
    phase2_kernel<<<NBK, 256, 0, stream>>>(bcnt, bbuf, cnt, slot);

    // pass 1: agg(hbf->A) + chain T2=[W2;b2]@W3 + ub = S·(1+deg)
    agg_fused_kernel<<<NB_AGG + NB_CHAIN + SPMV_BLOCKS, 64, 0, stream>>>(
        hbf, cnt, slot, bufA, W2, b2, W3, T2, nullptr, ub);
    // pass 2: agg(A->B) + chain T3=[W1;b1]@T2 + uc = S·ub
    agg_fused_kernel<<<NB_AGG + NB_CHAIN + SPMV_BLOCKS, 64, 0, stream>>>(
        bufA, cnt, slot, bufB, W1, b1, T2, T3, ub, uc);
    // pass 3: agg(B->A) + chain TW=[W0;b0]@T3
    agg_fused_kernel<<<NB_AGG + NB_CHAIN, 64, 0, stream>>>(
        bufB, cnt, slot, bufA, W0, b0, T3, TW, nullptr, nullptr);
    // pass 4: agg(A->B)
    agg_fused_kernel<<<NB_AGG, 64, 0, stream>>>(
        bufA, cnt, slot, bufB, nullptr, nullptr, nullptr, nullptr, nullptr, nullptr);

    // out = g @ WP + uc⊗v4 + ub⊗v3 + (1+cnt)⊗v2 + 1⊗b3
    gemm_kernel<<<N_NODES / TM, 256, 0, stream>>>(
        bufB, TW, out, cnt, ub, uc,
        T2 + 128 * D, T3 + 128 * D, TW + 128 * D, b3);
}

// Round 14
// 229.788 us; speedup vs baseline: 1.6317x; 1.6317x over previous
//
#include <hip/hip_runtime.h>

#define N_NODES 20000
#define N_EDGES 640000
#define D 128
#define CAP 128           // ELL capacity per node
#define NB_AGG 40000      // one 64-thread wave per (node, 64-feat slice): 20000 x 2
#define NB_CHAIN 129      // chain rider blocks: one row of [A;a](129x128)@B each
#define SPMV_BLOCKS 313   // ceil(20000/64)
#define NB_SC 1280        // scatter blocks: 8 XCD-groups x 160 stripes
#define E4 160000         // N_EDGES/4
#define E4_PER_STRIPE 1000
#define RANGE 2500        // N_NODES/8
#define NB_H2BF 1250      // 20000*16 uint4 / 256
#define TM 32             // final-GEMM tile rows

typedef unsigned int uint;
typedef unsigned short ushort;

__device__ __forceinline__ float bflo(uint u) { return __uint_as_float(u << 16); }
__device__ __forceinline__ float bfhi(uint u) { return __uint_as_float(u & 0xffff0000u); }
__device__ __forceinline__ uint pack2bf(float lo, float hi) {
    uint a = __float_as_uint(lo), b = __float_as_uint(hi);
    a += 0x7fffu + ((a >> 16) & 1u);
    b += 0x7fffu + ((b >> 16) & 1u);
    return (a >> 16) | (b & 0xffff0000u);
}

// ---------------- cnt = 0 ----------------

__global__ void zero_cnt_kernel(int* __restrict__ cnt) {
    int i = blockIdx.x * blockDim.x + threadIdx.x;
    if (i < N_NODES) cnt[i] = 0;
}

// ---------------- XCD-range-partitioned ELL scatter + h->bf16 riders ----------------
// blocks [0, NB_SC): group g = bid&7 handles dst range [g*RANGE, (g+1)*RANGE).
//   Group's slot region (640KB) stays L2-resident on one XCD -> lines absorb ~16
//   writes before one near-full eviction (vs per-write sector churn). Groups
//   re-read the edge list (8x41MB sequential, cheap). Heuristic only: any
//   group-block may run anywhere; correctness independent of placement.
// blocks [NB_SC, +NB_H2BF): h (f32) -> bf16 packed rows.

__global__ void scatter_h2bf_kernel(const int4* __restrict__ src4, const int4* __restrict__ dst4,
                                    int* __restrict__ cnt, ushort* __restrict__ slot,
                                    const float4* __restrict__ hin, uint4* __restrict__ hbf) {
    int bid = blockIdx.x;
    int t = threadIdx.x;
    if (bid < NB_SC) {
        int g  = bid & 7;
        int st = bid >> 3;
        int lo = g * RANGE, hiR = lo + RANGE;
        int e4lo = st * E4_PER_STRIPE;
        int e4hi = e4lo + E4_PER_STRIPE; if (e4hi > E4) e4hi = E4;
        for (int e4 = e4lo + t; e4 < e4hi; e4 += 256) {
            int4 s = src4[e4];
            int4 d = dst4[e4];
            if (d.x >= lo && d.x < hiR) slot[d.x * CAP + atomicAdd(&cnt[d.x], 1)] = (ushort)s.x;
            if (d.y >= lo && d.y < hiR) slot[d.y * CAP + atomicAdd(&cnt[d.y], 1)] = (ushort)s.y;
            if (d.z >= lo && d.z < hiR) slot[d.z * CAP + atomicAdd(&cnt[d.z], 1)] = (ushort)s.z;
            if (d.w >= lo && d.w < hiR) slot[d.w * CAP + atomicAdd(&cnt[d.w], 1)] = (ushort)s.w;
        }
    } else {
        int i = (bid - NB_SC) * 256 + t;   // uint4 index
        float4 f0 = hin[i * 2];
        float4 f1 = hin[i * 2 + 1];
        uint4 o;
        o.x = pack2bf(f0.x, f0.y); o.y = pack2bf(f0.z, f0.w);
        o.z = pack2bf(f1.x, f1.y); o.w = pack2bf(f1.z, f1.w);
        hbf[i] = o;
    }
}

// ---------------- fused agg pass (bf16 payloads, f32 accumulate) ----------------
// blocks [0, NB_AGG): one wave per (node, slice of 64 feats). Each edge-slice is
//   ONE 128B line. slice = (bid&7)>>2 keeps each slice's 2.56MB line set in an
//   XCD-quad's L2s (perf heuristic only). 8 slots x 8 lanes x uint4(8 bf16).
// blocks [NB_AGG, +129) when cO != null: chain row cO[row] = ([cA;cbias] @ cB)[row].
// remaining blocks when uout != null: degree SpMV.
//   uin != null:  uout[i] = uin[i] + sum uin[nbr]
//   uin == null:  uout[i] = 1+2c+sum cnt[nbr]  (= S·(1+deg))

__global__ __launch_bounds__(64) void agg_fused_kernel(
        const uint4* __restrict__ hbf, const int* __restrict__ cnt,
        const ushort* __restrict__ slot, uint4* __restrict__ xbf,
        const float* __restrict__ cA, const float* __restrict__ cbias,
        const float* __restrict__ cB, float* __restrict__ cO,
        const float* __restrict__ uin, float* __restrict__ uout) {
    int bid = blockIdx.x;
    int t = threadIdx.x;

    if (bid >= NB_AGG) {
        int cb = bid - NB_AGG;
        if (cO && cb < NB_CHAIN) {
            // chain: row cb of [cA; cbias^T] @ cB; 64 threads x 2 cols
            const float* Ar = (cb < 128) ? &cA[cb * 128] : cbias;
            int c0 = t, c1 = t + 64;
            float s0 = 0.f, s1 = 0.f;
            for (int k = 0; k < 128; ++k) {
                float a = Ar[k];
                s0 += a * cB[k * 128 + c0];
                s1 += a * cB[k * 128 + c1];
            }
            cO[cb * 128 + c0] = s0;
            cO[cb * 128 + c1] = s1;
        } else if (uout) {
            int sb = cb - (cO ? NB_CHAIN : 0);
            int node = sb * 64 + t;
            if (node < N_NODES) {
                int c = cnt[node];
                const ushort* sl = &slot[node * CAP];
                float s;
                if (uin) {
                    s = uin[node];
                    for (int k = 0; k < c; ++k) s += uin[sl[k]];
                } else {
                    s = 1.0f + 2.0f * (float)c;
                    for (int k = 0; k < c; ++k) s += (float)cnt[sl[k]];
                }
                uout[node] = s;
            }
        }
        return;
    }

    // ---- aggregation ----
    int r = bid & 7;
    int q = bid >> 3;
    int slice = r >> 2;           // 0..1 (fixed per block -> XCD-quad affinity)
    int node  = q * 4 + (r & 3);  // 0..19999
    int lo = node * CAP;
    int hi = lo + cnt[node];
    int slot8 = t >> 3;           // 0..7
    int fl    = t & 7;            // uint4 within the 8-uint4 slice
    int soff  = slice * 8 + fl;   // uint4 index within 16-uint4 row

    uint4 sv = hbf[(size_t)node * 16 + soff];   // self row slice, issued early

    float a0 = 0.f, a1 = 0.f, a2 = 0.f, a3 = 0.f;
    float a4 = 0.f, a5 = 0.f, a6 = 0.f, a7 = 0.f;

#define ACC8(v) do { \
        a0 += bflo((v).x); a1 += bfhi((v).x); \
        a2 += bflo((v).y); a3 += bfhi((v).y); \
        a4 += bflo((v).z); a5 += bfhi((v).z); \
        a6 += bflo((v).w); a7 += bfhi((v).w); } while (0)

    int k = lo + slot8;
    for (; k + 24 < hi; k += 32) {    // 4 line-gathers in flight per slot
        int s0 = slot[k];
        int s1 = slot[k + 8];
        int s2 = slot[k + 16];
        int s3 = slot[k + 24];
        uint4 v0 = hbf[(size_t)s0 * 16 + soff];
        uint4 v1 = hbf[(size_t)s1 * 16 + soff];
        uint4 v2 = hbf[(size_t)s2 * 16 + soff];
        uint4 v3 = hbf[(size_t)s3 * 16 + soff];
        ACC8(v0); ACC8(v1); ACC8(v2); ACC8(v3);
    }
    for (; k < hi; k += 8) {
        int s0 = slot[k];
        uint4 v0 = hbf[(size_t)s0 * 16 + soff];
        ACC8(v0);
    }
#undef ACC8

    // reduce across the 8 slots (lane bits 3,4,5)
    a0 += __shfl_xor(a0, 8);  a1 += __shfl_xor(a1, 8);
    a2 += __shfl_xor(a2, 8);  a3 += __shfl_xor(a3, 8);
    a4 += __shfl_xor(a4, 8);  a5 += __shfl_xor(a5, 8);
    a6 += __shfl_xor(a6, 8);  a7 += __shfl_xor(a7, 8);
    a0 += __shfl_xor(a0, 16); a1 += __shfl_xor(a1, 16);
    a2 += __shfl_xor(a2, 16); a3 += __shfl_xor(a3, 16);
    a4 += __shfl_xor(a4, 16); a5 += __shfl_xor(a5, 16);
    a6 += __shfl_xor(a6, 16); a7 += __shfl_xor(a7, 16);
    a0 += __shfl_xor(a0, 32); a1 += __shfl_xor(a1, 32);
    a2 += __shfl_xor(a2, 32); a3 += __shfl_xor(a3, 32);
    a4 += __shfl_xor(a4, 32); a5 += __shfl_xor(a5, 32);
    a6 += __shfl_xor(a6, 32); a7 += __shfl_xor(a7, 32);

    if (t < 8) {   // slot 0, fl == t
        a0 += bflo(sv.x); a1 += bfhi(sv.x);
        a2 += bflo(sv.y); a3 += bfhi(sv.y);
        a4 += bflo(sv.z); a5 += bfhi(sv.z);
        a6 += bflo(sv.w); a7 += bfhi(sv.w);
        uint4 o;
        o.x = pack2bf(a0, a1); o.y = pack2bf(a2, a3);
        o.z = pack2bf(a4, a5); o.w = pack2bf(a6, a7);
        xbf[(size_t)node * 16 + soff] = o;
    }
}

// ---------------- final GEMM: out = g @ WP + uc⊗v4 + ub⊗v3 + (1+cnt)⊗v2 + 1⊗b3 ----------------

__global__ __launch_bounds__(256) void gemm_kernel(const uint4* __restrict__ xb,
                                                   const float* __restrict__ W,
                                                   float* __restrict__ out,
                                                   const int* __restrict__ cnt,
                                                   const float* __restrict__ ub,
                                                   const float* __restrict__ uc,
                                                   const float* __restrict__ v2p,
                                                   const float* __restrict__ v3p,
                                                   const float* __restrict__ v4p,
                                                   const float* __restrict__ v1p) {
    __shared__ float Xs[TM][D];
    int t = threadIdx.x;
    int row0 = blockIdx.x * TM;

    for (int i = t; i < TM * 16; i += 256) {
        int rr  = i >> 4;
        int c16 = i & 15;
        uint4 u = xb[(size_t)(row0 + rr) * 16 + c16];
        float4 f0 = make_float4(bflo(u.x), bfhi(u.x), bflo(u.y), bfhi(u.y));
        float4 f1 = make_float4(bflo(u.z), bfhi(u.z), bflo(u.w), bfhi(u.w));
        *((float4*)&Xs[rr][c16 * 8])     = f0;
        *((float4*)&Xs[rr][c16 * 8 + 4]) = f1;
    }
    __syncthreads();

    int cg = t & 31;
    int rg = t >> 5;
    int j0 = cg * 4;
    int r0 = rg * 4;

    float acc[4][4];
    #pragma unroll
    for (int i = 0; i < 4; ++i) {
        acc[i][0] = 0.f; acc[i][1] = 0.f; acc[i][2] = 0.f; acc[i][3] = 0.f;
    }

    for (int k4 = 0; k4 < D; k4 += 4) {
        float4 w0 = *((const float4*)&W[(k4 + 0) * D + j0]);
        float4 w1 = *((const float4*)&W[(k4 + 1) * D + j0]);
        float4 w2 = *((const float4*)&W[(k4 + 2) * D + j0]);
        float4 w3 = *((const float4*)&W[(k4 + 3) * D + j0]);
        #pragma unroll
        for (int i = 0; i < 4; ++i) {
            float4 xv = *((const float4*)&Xs[r0 + i][k4]);
            acc[i][0] += xv.x * w0.x; acc[i][0] += xv.y * w1.x;
            acc[i][0] += xv.z * w2.x; acc[i][0] += xv.w * w3.x;
            acc[i][1] += xv.x * w0.y; acc[i][1] += xv.y * w1.y;
            acc[i][1] += xv.z * w2.y; acc[i][1] += xv.w * w3.y;
            acc[i][2] += xv.x * w0.z; acc[i][2] += xv.y * w1.z;
            acc[i][2] += xv.z * w2.z; acc[i][2] += xv.w * w3.z;
            acc[i][3] += xv.x * w0.w; acc[i][3] += xv.y * w1.w;
            acc[i][3] += xv.z * w2.w; acc[i][3] += xv.w * w3.w;
        }
    }

    float4 v1 = *((const float4*)&v1p[j0]);
    float4 v2 = *((const float4*)&v2p[j0]);
    float4 v3 = *((const float4*)&v3p[j0]);
    float4 v4 = *((const float4*)&v4p[j0]);

    #pragma unroll
    for (int i = 0; i < 4; ++i) {
        int ra = row0 + r0 + i;
        float aa = 1.0f + (float)cnt[ra];
        float ab = ub[ra], ac = uc[ra];
        float o0 = acc[i][0] + ac * v4.x + ab * v3.x + aa * v2.x + v1.x;
        float o1 = acc[i][1] + ac * v4.y + ab * v3.y + aa * v2.y + v1.y;
        float o2 = acc[i][2] + ac * v4.z + ab * v3.z + aa * v2.z + v1.z;
        float o3 = acc[i][3] + ac * v4.w + ab * v3.w + aa * v2.w + v1.w;
        *((float4*)&out[(size_t)ra * D + j0]) = make_float4(o0, o1, o2, o3);
    }
}

// ---------------- launch ----------------

extern "C" void kernel_launch(void* const* d_in, const int* in_sizes, int n_in,
                              void* d_out, int out_size, void* d_ws, size_t ws_size,
                              hipStream_t stream) {
    const float* h   = (const float*)d_in[0];
    const int*   ei  = (const int*)d_in[1];
    const int*   src = ei;
    const int*   dst = ei + N_EDGES;
    const float* W0 = (const float*)d_in[2]; const float* b0 = (const float*)d_in[3];
    const float* W1 = (const float*)d_in[4]; const float* b1 = (const float*)d_in[5];
    const float* W2 = (const float*)d_in[6]; const float* b2 = (const float*)d_in[7];
    const float* W3 = (const float*)d_in[8]; const float* b3 = (const float*)d_in[9];
    float* out = (float*)d_out;

    char* ws = (char*)d_ws;
    auto alloc = [&](size_t bytes) {
        char* p = ws;
        ws += (bytes + 255) & ~(size_t)255;
        return p;
    };
    int*    cnt  = (int*)alloc(N_NODES * sizeof(int));
    ushort* slot = (ushort*)alloc((size_t)N_NODES * CAP * sizeof(ushort));
    uint4*  hbf  = (uint4*)alloc((size_t)N_NODES * 16 * sizeof(uint4));  // bf16 h
    uint4*  bufA = (uint4*)alloc((size_t)N_NODES * 16 * sizeof(uint4));
    uint4*  bufB = (uint4*)alloc((size_t)N_NODES * 16 * sizeof(uint4));
    float*  T2   = (float*)alloc(129 * D * sizeof(float));  // [W2W3 ; v2]
    float*  T3   = (float*)alloc(129 * D * sizeof(float));  // [W1W2W3 ; v3]
    float*  TW   = (float*)alloc(129 * D * sizeof(float));  // [W0W1W2W3 ; v4]
    float*  ub   = (float*)alloc(N_NODES * sizeof(float));  // S²·1
    float*  uc   = (float*)alloc(N_NODES * sizeof(float));  // S³·1

    // cnt = 0
    zero_cnt_kernel<<<(N_NODES + 255) / 256, 256, 0, stream>>>(cnt);

    // XCD-range-partitioned ELL scatter + h->bf16 riders; cnt ends as degree
    scatter_h2bf_kernel<<<NB_SC + NB_H2BF, 256, 0, stream>>>(
        (const int4*)src, (const int4*)dst, cnt, slot, (const float4*)h, hbf);

    // pass 1: agg(hbf->A) + chain T2=[W2;b2]@W3 + ub = S·(1+deg)
    agg_fused_kernel<<<NB_AGG + NB_CHAIN + SPMV_BLOCKS, 64, 0, stream>>>(
        hbf, cnt, slot, bufA, W2, b2, W3, T2, nullptr, ub);
    // pass 2: agg(A->B) + chain T3=[W1;b1]@T2 + uc = S·ub
    agg_fused_kernel<<<NB_AGG + NB_CHAIN + SPMV_BLOCKS, 64, 0, stream>>>(
        bufA, cnt, slot, bufB, W1, b1, T2, T3, ub, uc);
    // pass 3: agg(B->A) + chain TW=[W0;b0]@T3
    agg_fused_kernel<<<NB_AGG + NB_CHAIN, 64, 0, stream>>>(
        bufB, cnt, slot, bufA, W0, b0, T3, TW, nullptr, nullptr);
    // pass 4: agg(A->B)
    agg_fused_kernel<<<NB_AGG, 64, 0, stream>>>(
        bufA, cnt, slot, bufB, nullptr, nullptr, nullptr, nullptr, nullptr, nullptr);

    // out = g @ WP + uc⊗v4 + ub⊗v3 + (1+cnt)⊗v2 + 1⊗b3
    gemm_kernel<<<N_NODES / TM, 256, 0, stream>>>(
        bufB, TW, out, cnt, ub, uc,
        T2 + 128 * D, T3 + 128 * D, TW + 128 * D, b3);
}